// Round 1
// baseline (138.089 us; speedup 1.0000x reference)
//
#include <hip/hip_runtime.h>
#include <hip/hip_bf16.h>

// Problem constants (fixed by setup_inputs): B=4096, d=128, M=8192, C=16
#define B_ROWS 4096
#define D_K    128
#define M_ROWS 8192
#define N_TOT  12288   // B_ROWS + M_ROWS
#define NJT    96      // N_TOT / 128  (j-tiles of 128)
#define NJT_B  32      // B_ROWS / 128 (in-batch j-tiles)

typedef __attribute__((ext_vector_type(8))) short short8;
typedef __attribute__((ext_vector_type(4))) float floatx4;

// ---------------------------------------------------------------------------
// Kernel 1: normalize rows of f (first B_ROWS) and f_neg (next M_ROWS) into a
// single bf16 matrix G[N_TOT][D_K]; also build the 16-bin class histogram.
// One wave per row; lane holds 2 floats.
// ---------------------------------------------------------------------------
__global__ __launch_bounds__(256) void nrm_kernel(
    const float* __restrict__ f, const float* __restrict__ fneg,
    const int* __restrict__ labels, __hip_bfloat16* __restrict__ G,
    int* __restrict__ hist)
{
    const int wave = threadIdx.x >> 6;
    const int lane = threadIdx.x & 63;
    const int row  = blockIdx.x * 4 + wave;           // grid is exact: 3072*4
    const float* src = (row < B_ROWS) ? (f + (size_t)row * D_K)
                                      : (fneg + (size_t)(row - B_ROWS) * D_K);
    float2 v = *reinterpret_cast<const float2*>(src + lane * 2);
    float ss = v.x * v.x + v.y * v.y;
    #pragma unroll
    for (int m = 1; m < 64; m <<= 1) ss += __shfl_xor(ss, m, 64);
    const float scale = 1.0f / fmaxf(sqrtf(ss), 1e-8f);   // 1/max(||x||, EPS)
    __hip_bfloat162 o;
    o.x = __float2bfloat16(v.x * scale);
    o.y = __float2bfloat16(v.y * scale);
    *reinterpret_cast<__hip_bfloat162*>(G + (size_t)row * D_K + lane * 2) = o;
    if (row < B_ROWS && lane == 0) atomicAdd(&hist[labels[row]], 1);
}

// ---------------------------------------------------------------------------
// Kernel 2: fused sim + exp + row-reduce.
// Block = 256 thr = 4 waves, block tile = 64(i) x 128(j).
// Wave (wi,wj) computes a 32x64 tile via 2x4 fragments of
// v_mfma_f32_16x16x32_bf16 over K=128 (4 k-steps).
// Fragment layout (verified m89/m92): A: row=l&15, k=(l>>4)*8+e (contig 8);
// B from row-major [n][k] (our G): n=l&15, same k — contiguous bf16x8 loads.
// C/D: col=l&15, row=(l>>4)*4+reg.
// Epilogue: exp (excluding self), positive-sim accumulation, 16-lane-group
// shfl reduce, cross-wave LDS combine, write per-(jtile,row) partials.
// ---------------------------------------------------------------------------
__global__ __launch_bounds__(256) void sim_kernel(
    const __hip_bfloat16* __restrict__ G, const int* __restrict__ labels,
    float* __restrict__ part_d, float* __restrict__ part_p)
{
    const int jt   = blockIdx.x;          // 0..95
    const int it   = blockIdx.y;          // 0..63
    const int tid  = threadIdx.x;
    const int wave = tid >> 6;
    const int lane = tid & 63;
    const int wi   = wave >> 1;           // 0..1 : i-half
    const int wj   = wave & 1;            // 0..1 : j-half
    const int i0   = it * 64 + wi * 32;
    const int j0   = jt * 128 + wj * 64;
    const bool inbatch = (jt < NJT_B);

    __shared__ int   ilab[64];
    __shared__ int   jlab[128];
    __shared__ float red_d[2][64];
    __shared__ float red_p[2][64];

    if (tid < 64)  ilab[tid] = labels[it * 64 + tid];
    if (inbatch && tid < 128) jlab[tid] = labels[jt * 128 + tid];
    __syncthreads();

    const int r16  = lane & 15;
    const int grp  = lane >> 4;
    const int koff = grp * 8;

    const __hip_bfloat16* Arow = G + (size_t)(i0 + r16) * D_K + koff;
    const __hip_bfloat16* Brow = G + (size_t)(j0 + r16) * D_K + koff;

    floatx4 acc[2][4];
    #pragma unroll
    for (int a = 0; a < 2; ++a)
        #pragma unroll
        for (int b = 0; b < 4; ++b)
            acc[a][b] = (floatx4){0.f, 0.f, 0.f, 0.f};

    #pragma unroll
    for (int ks = 0; ks < 4; ++ks) {
        const int k = ks * 32;
        short8 afr[2], bfr[4];
        #pragma unroll
        for (int a = 0; a < 2; ++a)
            afr[a] = *reinterpret_cast<const short8*>(Arow + (size_t)a * 16 * D_K + k);
        #pragma unroll
        for (int b = 0; b < 4; ++b)
            bfr[b] = *reinterpret_cast<const short8*>(Brow + (size_t)b * 16 * D_K + k);
        #pragma unroll
        for (int a = 0; a < 2; ++a)
            #pragma unroll
            for (int b = 0; b < 4; ++b)
                acc[a][b] = __builtin_amdgcn_mfma_f32_16x16x32_bf16(
                    afr[a], bfr[b], acc[a][b], 0, 0, 0);
    }

    // Epilogue: per (ai, reg) this lane owns sim[ig][j0 + bj*16 + r16].
    #pragma unroll
    for (int ai = 0; ai < 2; ++ai) {
        #pragma unroll
        for (int reg = 0; reg < 4; ++reg) {
            const int ig  = i0 + ai * 16 + grp * 4 + reg;   // global i
            const int myl = ilab[ig - it * 64];
            float dpart = 0.f, ppart = 0.f;
            #pragma unroll
            for (int bj = 0; bj < 4; ++bj) {
                const float v  = acc[ai][bj][reg];
                const int   jg = j0 + bj * 16 + r16;        // global j
                if (inbatch) {
                    const bool self = (jg == ig);
                    dpart += self ? 0.f : __expf(v);
                    if (!self && jlab[jg - jt * 128] == myl) ppart += v;
                } else {
                    dpart += __expf(v);
                }
            }
            // reduce over the 16 columns (lanes within 16-group)
            #pragma unroll
            for (int m = 1; m < 16; m <<= 1) {
                dpart += __shfl_xor(dpart, m, 64);
                ppart += __shfl_xor(ppart, m, 64);
            }
            if (r16 == 0) {
                const int rloc = wi * 32 + ai * 16 + grp * 4 + reg;
                red_d[wj][rloc] = dpart;
                red_p[wj][rloc] = ppart;
            }
        }
    }
    __syncthreads();

    if (tid < 64) {
        const float dv = red_d[0][tid] + red_d[1][tid];
        part_d[(size_t)jt * B_ROWS + it * 64 + tid] = dv;
        if (inbatch) {
            const float pv = red_p[0][tid] + red_p[1][tid];
            part_p[(size_t)jt * B_ROWS + it * 64 + tid] = pv;
        }
    }
}

// ---------------------------------------------------------------------------
// Kernel 3: finalize. One thread per row i: sum partials, compute loss_i,
// block-reduce, atomicAdd mean into out.
// ---------------------------------------------------------------------------
__global__ __launch_bounds__(256) void fin_kernel(
    const float* __restrict__ part_d, const float* __restrict__ part_p,
    const int* __restrict__ labels, const int* __restrict__ hist,
    float* __restrict__ out)
{
    const int i = blockIdx.x * 256 + threadIdx.x;   // 16 blocks x 256 = 4096
    float dsum = 0.f, psum = 0.f;
    for (int jt = 0; jt < NJT; ++jt)   dsum += part_d[(size_t)jt * B_ROWS + i];
    for (int jt = 0; jt < NJT_B; ++jt) psum += part_p[(size_t)jt * B_ROWS + i];
    const float npos = (float)(hist[labels[i]] - 1);
    float loss = __logf(dsum) - psum / npos;
    #pragma unroll
    for (int m = 1; m < 64; m <<= 1) loss += __shfl_xor(loss, m, 64);
    __shared__ float ws[4];
    if ((threadIdx.x & 63) == 0) ws[threadIdx.x >> 6] = loss;
    __syncthreads();
    if (threadIdx.x == 0) {
        const float s = ws[0] + ws[1] + ws[2] + ws[3];
        atomicAdd(out, s * (1.0f / (float)B_ROWS));
    }
}

// ---------------------------------------------------------------------------
extern "C" void kernel_launch(void* const* d_in, const int* in_sizes, int n_in,
                              void* d_out, int out_size, void* d_ws, size_t ws_size,
                              hipStream_t stream) {
    const float* f      = (const float*)d_in[0];
    const float* fneg   = (const float*)d_in[1];
    const int*   labels = (const int*)d_in[2];
    float*       out    = (float*)d_out;

    char* ws = (char*)d_ws;
    // Workspace layout (bytes):
    //   G      : 12288*128*2 = 3,145,728
    //   part_d : 96*4096*4   = 1,572,864
    //   part_p : 32*4096*4   =   524,288
    //   hist   : 64
    __hip_bfloat16* G      = (__hip_bfloat16*)(ws);
    float*          part_d = (float*)(ws + 3145728);
    float*          part_p = (float*)(ws + 3145728 + 1572864);
    int*            hist   = (int*)(ws + 3145728 + 1572864 + 524288);

    hipMemsetAsync(hist, 0, 64, stream);
    hipMemsetAsync(out, 0, sizeof(float), stream);

    nrm_kernel<<<N_TOT / 4, 256, 0, stream>>>(f, fneg, labels, G, hist);

    dim3 gridS(NJT, B_ROWS / 64);   // (96, 64)
    sim_kernel<<<gridS, 256, 0, stream>>>(G, labels, part_d, part_p);

    fin_kernel<<<B_ROWS / 256, 256, 0, stream>>>(part_d, part_p, labels, hist, out);
}

// Round 2
// 86.132 us; speedup vs baseline: 1.6032x; 1.6032x over previous
//
#include <hip/hip_runtime.h>
#include <hip/hip_bf16.h>

// Problem constants (fixed by setup_inputs): B=4096, d=128, M=8192, C=16
#define B_ROWS 4096
#define D_K    128
#define M_ROWS 8192
#define N_TOT  12288   // B_ROWS + M_ROWS
#define NJT    96      // N_TOT / 128  (j-tiles of 128 cols)
#define NJT_B  32      // B_ROWS / 128 (in-batch j-tiles)
#define NCHUNK 16      // j-chunks
#define JT_PER_CHUNK 6 // 96 / 16

typedef __attribute__((ext_vector_type(8))) short short8;
typedef __attribute__((ext_vector_type(4))) float floatx4;

// ---------------------------------------------------------------------------
// Kernel 1: normalize rows of f (first B_ROWS) and f_neg (next M_ROWS) into a
// single bf16 matrix G[N_TOT][D_K]. One wave per row; lane holds 2 floats.
// ---------------------------------------------------------------------------
__global__ __launch_bounds__(256) void nrm_kernel(
    const float* __restrict__ f, const float* __restrict__ fneg,
    __hip_bfloat16* __restrict__ G)
{
    const int wave = threadIdx.x >> 6;
    const int lane = threadIdx.x & 63;
    const int row  = blockIdx.x * 4 + wave;           // grid exact: 3072*4
    const float* src = (row < B_ROWS) ? (f + (size_t)row * D_K)
                                      : (fneg + (size_t)(row - B_ROWS) * D_K);
    float2 v = *reinterpret_cast<const float2*>(src + lane * 2);
    float ss = v.x * v.x + v.y * v.y;
    #pragma unroll
    for (int m = 1; m < 64; m <<= 1) ss += __shfl_xor(ss, m, 64);
    const float scale = 1.0f / fmaxf(sqrtf(ss), 1e-8f);   // 1/max(||x||, EPS)
    __hip_bfloat162 o;
    o.x = __float2bfloat16(v.x * scale);
    o.y = __float2bfloat16(v.y * scale);
    *reinterpret_cast<__hip_bfloat162*>(G + (size_t)row * D_K + lane * 2) = o;
}

// ---------------------------------------------------------------------------
// Kernel 2: fused sim + exp + row-accumulate, j-looped.
// Grid (NCHUNK, 64). Block = 256 thr = 4 waves; block i-tile = 64 rows.
// Wave (wi,wj): rows i0 = it*64+wi*32 (32 rows), cols j0 = jt*128+wj*64.
// A-fragments (2 frag x 4 ksteps = 32 VGPRs) loaded ONCE, resident across the
// 6-iteration j-loop. Per iter: 16 B-fragment loads, 32 MFMAs, exp+acc into
// per-lane registers. Single 16-lane shuffle reduce at the end.
// Fragment layout identical to R1 kernel (verified passing):
//   A/B: row = l&15, k = (l>>4)*8 + e (contiguous bf16x8)
//   C/D: col = l&15, row = (l>>4)*4 + reg
// ---------------------------------------------------------------------------
__global__ __launch_bounds__(256) void sim_kernel(
    const __hip_bfloat16* __restrict__ G, const int* __restrict__ labels,
    float* __restrict__ part_d, float* __restrict__ part_p)
{
    const int jc   = blockIdx.x;          // 0..15
    const int it   = blockIdx.y;          // 0..63
    const int tid  = threadIdx.x;
    const int wave = tid >> 6;
    const int lane = tid & 63;
    const int wi   = wave >> 1;           // 0..1 : i-half
    const int wj   = wave & 1;            // 0..1 : j-half
    const int i0   = it * 64 + wi * 32;

    const int r16  = lane & 15;
    const int grp  = lane >> 4;
    const int koff = grp * 8;

    // Resident A fragments: [ai][ks]
    const __hip_bfloat16* Arow = G + (size_t)(i0 + r16) * D_K + koff;
    short8 afr[2][4];
    #pragma unroll
    for (int a = 0; a < 2; ++a)
        #pragma unroll
        for (int ks = 0; ks < 4; ++ks)
            afr[a][ks] = *reinterpret_cast<const short8*>(
                Arow + (size_t)a * 16 * D_K + ks * 32);

    // My row labels (8 per lane), needed for in-batch iters
    int myl[2][4];
    #pragma unroll
    for (int a = 0; a < 2; ++a)
        #pragma unroll
        for (int r = 0; r < 4; ++r)
            myl[a][r] = labels[i0 + a * 16 + grp * 4 + r];

    float dsum[2][4], psum[2][4];
    #pragma unroll
    for (int a = 0; a < 2; ++a)
        #pragma unroll
        for (int r = 0; r < 4; ++r) { dsum[a][r] = 0.f; psum[a][r] = 0.f; }

    #pragma unroll 2
    for (int t = 0; t < JT_PER_CHUNK; ++t) {
        const int jt = jc * JT_PER_CHUNK + t;
        const int j0 = jt * 128 + wj * 64;
        const __hip_bfloat16* Brow = G + (size_t)(j0 + r16) * D_K + koff;

        floatx4 acc[2][4];
        #pragma unroll
        for (int a = 0; a < 2; ++a)
            #pragma unroll
            for (int b = 0; b < 4; ++b)
                acc[a][b] = (floatx4){0.f, 0.f, 0.f, 0.f};

        #pragma unroll
        for (int ks = 0; ks < 4; ++ks) {
            short8 bfr[4];
            #pragma unroll
            for (int b = 0; b < 4; ++b)
                bfr[b] = *reinterpret_cast<const short8*>(
                    Brow + (size_t)b * 16 * D_K + ks * 32);
            #pragma unroll
            for (int a = 0; a < 2; ++a)
                #pragma unroll
                for (int b = 0; b < 4; ++b)
                    acc[a][b] = __builtin_amdgcn_mfma_f32_16x16x32_bf16(
                        afr[a][ks], bfr[b], acc[a][b], 0, 0, 0);
        }

        const bool inb = (jt < NJT_B);
        if (inb) {
            // column labels for this lane (4 cols)
            int jl[4];
            #pragma unroll
            for (int b = 0; b < 4; ++b) jl[b] = labels[j0 + b * 16 + r16];
            #pragma unroll
            for (int a = 0; a < 2; ++a) {
                #pragma unroll
                for (int r = 0; r < 4; ++r) {
                    const int ig = i0 + a * 16 + grp * 4 + r;
                    #pragma unroll
                    for (int b = 0; b < 4; ++b) {
                        const float v  = acc[a][b][r];
                        const int   jg = j0 + b * 16 + r16;
                        const bool self = (jg == ig);
                        dsum[a][r] += self ? 0.f : __expf(v);
                        psum[a][r] += (!self && jl[b] == myl[a][r]) ? v : 0.f;
                    }
                }
            }
        } else {
            #pragma unroll
            for (int a = 0; a < 2; ++a)
                #pragma unroll
                for (int r = 0; r < 4; ++r)
                    #pragma unroll
                    for (int b = 0; b < 4; ++b)
                        dsum[a][r] += __expf(acc[a][b][r]);
        }
    }

    // Single 16-lane reduce per accumulator slot
    #pragma unroll
    for (int a = 0; a < 2; ++a) {
        #pragma unroll
        for (int r = 0; r < 4; ++r) {
            #pragma unroll
            for (int m = 1; m < 16; m <<= 1) {
                dsum[a][r] += __shfl_xor(dsum[a][r], m, 64);
                psum[a][r] += __shfl_xor(psum[a][r], m, 64);
            }
        }
    }
    if (r16 == 0) {
        #pragma unroll
        for (int a = 0; a < 2; ++a) {
            #pragma unroll
            for (int r = 0; r < 4; ++r) {
                const int row = it * 64 + wi * 32 + a * 16 + grp * 4 + r;
                const size_t idx = (size_t)(jc * 2 + wj) * B_ROWS + row;
                part_d[idx] = dsum[a][r];
                part_p[idx] = psum[a][r];
            }
        }
    }
}

// ---------------------------------------------------------------------------
// Kernel 3: per-row finalize + per-block sum (no global atomics, no memsets).
// 16 blocks x 256 thr; histogram built per-block in LDS.
// ---------------------------------------------------------------------------
__global__ __launch_bounds__(256) void fin1_kernel(
    const float* __restrict__ part_d, const float* __restrict__ part_p,
    const int* __restrict__ labels, float* __restrict__ bsum)
{
    const int tid = threadIdx.x;
    const int i   = blockIdx.x * 256 + tid;
    __shared__ int lh[16];
    if (tid < 16) lh[tid] = 0;
    __syncthreads();
    for (int j = tid; j < B_ROWS; j += 256) atomicAdd(&lh[labels[j]], 1);
    __syncthreads();

    float ds = 0.f, ps = 0.f;
    #pragma unroll
    for (int c = 0; c < 2 * NCHUNK; ++c) {
        ds += part_d[(size_t)c * B_ROWS + i];
        ps += part_p[(size_t)c * B_ROWS + i];
    }
    const float npos = (float)(lh[labels[i]] - 1);
    float loss = __logf(ds) - ps / npos;
    #pragma unroll
    for (int m = 1; m < 64; m <<= 1) loss += __shfl_xor(loss, m, 64);
    __shared__ float w4[4];
    if ((tid & 63) == 0) w4[tid >> 6] = loss;
    __syncthreads();
    if (tid == 0) bsum[blockIdx.x] = w4[0] + w4[1] + w4[2] + w4[3];
}

// Kernel 4: final 16-value sum -> mean. One wave.
__global__ void fin2_kernel(const float* __restrict__ bsum, float* __restrict__ out)
{
    const int lane = threadIdx.x;
    float v = (lane < 16) ? bsum[lane] : 0.f;
    #pragma unroll
    for (int m = 1; m < 16; m <<= 1) v += __shfl_xor(v, m, 64);
    if (lane == 0) out[0] = v * (1.0f / (float)B_ROWS);
}

// ---------------------------------------------------------------------------
extern "C" void kernel_launch(void* const* d_in, const int* in_sizes, int n_in,
                              void* d_out, int out_size, void* d_ws, size_t ws_size,
                              hipStream_t stream) {
    const float* f      = (const float*)d_in[0];
    const float* fneg   = (const float*)d_in[1];
    const int*   labels = (const int*)d_in[2];
    float*       out    = (float*)d_out;

    char* ws = (char*)d_ws;
    // Workspace layout (bytes):
    //   G      : 12288*128*2       = 3,145,728
    //   part_d : 32*4096*4         =   524,288
    //   part_p : 32*4096*4         =   524,288
    //   bsum   : 16*4              =        64
    __hip_bfloat16* G      = (__hip_bfloat16*)(ws);
    float*          part_d = (float*)(ws + 3145728);
    float*          part_p = (float*)(ws + 3145728 + 524288);
    float*          bsum   = (float*)(ws + 3145728 + 524288 + 524288);

    nrm_kernel<<<N_TOT / 4, 256, 0, stream>>>(f, fneg, G);

    dim3 gridS(NCHUNK, B_ROWS / 64);   // (16, 64)
    sim_kernel<<<gridS, 256, 0, stream>>>(G, labels, part_d, part_p);

    fin1_kernel<<<NCHUNK, 256, 0, stream>>>(part_d, part_p, labels, bsum);
    fin2_kernel<<<1, 64, 0, stream>>>(bsum, out);
}